// Round 3
// baseline (108.454 us; speedup 1.0000x reference)
//
#include <hip/hip_runtime.h>
#include <math.h>

#define BSZ 512      // batch
#define FDIM 512     // features
#define NK 32        // num_kernels
#define DD 16        // dim_per_kernel
#define NDIM (NK*DD) // 512
#define OUTW (FDIM + NK)  // 544

// ---------------------------------------------------------------------------
// Kernel 1: m = x @ T (fp32 VALU), plus output prep (x -> out[:, :512],
// zero out[:, 512:544]).
//   Tile = 16 rows x 64 cols. grid 256 = (32 row-groups) x (8 col-octs),
//   256 threads (4 waves). x tile (16x512 = 32 KB) staged in LDS ONCE with
//   coalesced float4 loads (poison fill flushes L2/L3 every iteration, so
//   x/T are HBM-cold at ~900cyc; staging pays that latency once, covered by
//   4 waves). Hot loop: thread = 4 rows x 1 col; per 4-k step: 4 T loads
//   (unroll 8 -> 32 loads in flight per wave) + 4 uniform ds_read_b128 +
//   16 FMA. T L2 traffic = 32 re-reads x 1 MB = 32 MB (~1 us at L2 BW).
// ---------------------------------------------------------------------------
__global__ __launch_bounds__(256) void k_gemm(
    const float* __restrict__ x, const float* __restrict__ T,
    float* __restrict__ m, float* __restrict__ out) {
  __shared__ float xs[16][FDIM];  // 32 KB
  const int t  = threadIdx.x;
  const int b  = blockIdx.x;
  const int rg = b >> 3;           // row group 0..31 (rows rg*16..+16)
  const int cq = b & 7;            // col oct (cols cq*64..+64)
  const int col = cq * 64 + (t & 63);
  const int rq  = __builtin_amdgcn_readfirstlane(t >> 6);  // 0..3 per wave

  // stage x tile: 16 rows x 128 float4 = 2048 float4, 8 per thread, coalesced
#pragma unroll
  for (int q = 0; q < 8; ++q) {
    const int idx = q * 256 + t;       // 0..2047
    const int row = idx >> 7, c4 = idx & 127;
    *(float4*)&xs[row][c4 * 4] =
        *(const float4*)(x + (size_t)(rg * 16 + row) * FDIM + c4 * 4);
  }
  __syncthreads();

  float a0 = 0.f, a1 = 0.f, a2 = 0.f, a3 = 0.f;
#pragma unroll 8
  for (int kk = 0; kk < FDIM; kk += 4) {
    // 4 T loads (per-lane, coalesced 256B/wave); 32 in flight at unroll 8
    const float t0 = T[(size_t)(kk + 0) * NDIM + col];
    const float t1 = T[(size_t)(kk + 1) * NDIM + col];
    const float t2 = T[(size_t)(kk + 2) * NDIM + col];
    const float t3 = T[(size_t)(kk + 3) * NDIM + col];
    // x values: uniform LDS broadcast per wave (rq, kk uniform)
    const float4 x0 = *(const float4*)&xs[rq * 4 + 0][kk];
    const float4 x1 = *(const float4*)&xs[rq * 4 + 1][kk];
    const float4 x2 = *(const float4*)&xs[rq * 4 + 2][kk];
    const float4 x3 = *(const float4*)&xs[rq * 4 + 3][kk];
    a0 = fmaf(x0.x, t0, a0); a0 = fmaf(x0.y, t1, a0);
    a0 = fmaf(x0.z, t2, a0); a0 = fmaf(x0.w, t3, a0);
    a1 = fmaf(x1.x, t0, a1); a1 = fmaf(x1.y, t1, a1);
    a1 = fmaf(x1.z, t2, a1); a1 = fmaf(x1.w, t3, a1);
    a2 = fmaf(x2.x, t0, a2); a2 = fmaf(x2.y, t1, a2);
    a2 = fmaf(x2.z, t2, a2); a2 = fmaf(x2.w, t3, a2);
    a3 = fmaf(x3.x, t0, a3); a3 = fmaf(x3.y, t1, a3);
    a3 = fmaf(x3.z, t2, a3); a3 = fmaf(x3.w, t3, a3);
  }
  {
    const int r0 = rg * 16 + rq * 4;
    m[(size_t)(r0 + 0) * NDIM + col] = a0;
    m[(size_t)(r0 + 1) * NDIM + col] = a1;
    m[(size_t)(r0 + 2) * NDIM + col] = a2;
    m[(size_t)(r0 + 3) * NDIM + col] = a3;
  }

  // ---- output prep: 65536 threads over the grid ----
  const int g = b * 256 + t;
  {  // copy x -> out[:, :512]: 512 rows x 128 float4
    const int orow = g >> 7, c4 = g & 127;
    *(float4*)(out + (size_t)orow * OUTW + c4 * 4) =
        *(const float4*)(x + (size_t)orow * FDIM + c4 * 4);
  }
  if (g < 16384) {  // zero feats columns (out poisoned 0xAA pre-launch)
    const int orow = g >> 5, kk = g & 31;
    out[(size_t)orow * OUTW + FDIM + kk] = 0.f;
  }
}

// ---------------------------------------------------------------------------
// Kernel 2: feats[i,k] += sum_j exp(-sum_d |m[i,k,d]-m[j,k,d]|)
//   grid 1024 = (8 i-groups of 64) x (32 k) x (4 j-quarters), 256 thr
//   (4 waves) -> 4 blocks/CU, 16 waves/CU. B-slice m[jq*128..+128][16k..+16]
//   (8 KB) staged into LDS once (coalesced, one cold round-trip covered by
//   TLP); A fragment per-lane direct from global (one-time). Hot loop is
//   pure LDS-broadcast + VALU: per j, 4 uniform ds_read_b128 + 32 VALU
//   (v_sub + v_add-with-abs) + exp. VALU floor ~3.4 us chip-wide.
//   LDS-reduce 4 waves -> one atomicAdd per (i,k) per block (4 contenders;
//   k_gemm zero-inits feats).
// ---------------------------------------------------------------------------
__global__ __launch_bounds__(256) void k_dist(
    const float* __restrict__ m, float* __restrict__ out) {
  __shared__ float Bs[128 * DD];  // 8 KB
  __shared__ float red[256];
  const int t   = threadIdx.x;
  const int bid = blockIdx.x;
  const int ig  = bid >> 7;         // 0..7
  const int k   = (bid >> 2) & 31;  // 0..31
  const int jq  = bid & 3;          // j quarter
  const int lane = t & 63;
  const int w    = __builtin_amdgcn_readfirstlane(t >> 6);  // wave 0..3
  const int i    = ig * 64 + lane;

  // A fragment (per-lane): m[i][16k..+16), issued before the staging barrier
  const float4* ap = (const float4*)(m + (size_t)i * NDIM + k * DD);
  const float4 A0 = ap[0], A1 = ap[1], A2 = ap[2], A3 = ap[3];

  // stage B slice: 128 j-rows x 4 float4 = 512 float4, 2 per thread
  const float* mb = m + (size_t)(jq * 128) * NDIM + k * DD;
#pragma unroll
  for (int q = 0; q < 2; ++q) {
    const int idx = q * 256 + t;        // 0..511
    const int jrow = idx >> 2, part = idx & 3;
    *(float4*)&Bs[jrow * DD + part * 4] =
        *(const float4*)(mb + (size_t)jrow * NDIM + part * 4);
  }
  __syncthreads();

  float a[DD];
  a[0]=A0.x; a[1]=A0.y; a[2]=A0.z;  a[3]=A0.w;
  a[4]=A1.x; a[5]=A1.y; a[6]=A1.z;  a[7]=A1.w;
  a[8]=A2.x; a[9]=A2.y; a[10]=A2.z; a[11]=A2.w;
  a[12]=A3.x;a[13]=A3.y;a[14]=A3.z; a[15]=A3.w;

  const int jbase = w * 32;
  float f = 0.f;
#pragma unroll 4
  for (int j = 0; j < 32; ++j) {
    const float4* bp = (const float4*)&Bs[(jbase + j) * DD];  // uniform
    const float4 b0 = bp[0], b1 = bp[1], b2 = bp[2], b3 = bp[3];
    float d =
        fabsf(a[0]  - b0.x) + fabsf(a[1]  - b0.y) +
        fabsf(a[2]  - b0.z) + fabsf(a[3]  - b0.w) +
        fabsf(a[4]  - b1.x) + fabsf(a[5]  - b1.y) +
        fabsf(a[6]  - b1.z) + fabsf(a[7]  - b1.w) +
        fabsf(a[8]  - b2.x) + fabsf(a[9]  - b2.y) +
        fabsf(a[10] - b2.z) + fabsf(a[11] - b2.w) +
        fabsf(a[12] - b3.x) + fabsf(a[13] - b3.y) +
        fabsf(a[14] - b3.z) + fabsf(a[15] - b3.w);
    f += __expf(-d);
  }

  red[t] = f;
  __syncthreads();
  if (t < 64) {
    const float s = red[t] + red[t + 64] + red[t + 128] + red[t + 192];
    atomicAdd(out + (size_t)(ig * 64 + t) * OUTW + FDIM + k, s);
  }
}

extern "C" void kernel_launch(void* const* d_in, const int* in_sizes, int n_in,
                              void* d_out, int out_size, void* d_ws,
                              size_t ws_size, hipStream_t stream) {
  (void)in_sizes; (void)n_in; (void)out_size; (void)ws_size;
  const float* x = (const float*)d_in[0];
  const float* T = (const float*)d_in[1];
  float* out = (float*)d_out;
  float* m   = (float*)d_ws;  // [512][512] fp32, 1 MB

  hipLaunchKernelGGL(k_gemm, dim3(256), dim3(256), 0, stream, x, T, m, out);
  hipLaunchKernelGGL(k_dist, dim3(1024), dim3(256), 0, stream, m, out);
}

// Round 4
// 74.000 us; speedup vs baseline: 1.4656x; 1.4656x over previous
//
#include <hip/hip_runtime.h>
#include <math.h>

#define BSZ 512      // batch
#define FDIM 512     // features
#define NK 32        // num_kernels
#define DD 16        // dim_per_kernel
#define NDIM (NK*DD) // 512
#define OUTW (FDIM + NK)  // 544

// ---------------------------------------------------------------------------
// Kernel 1: m = x @ T (fp32 VALU), plus output prep (x -> out[:, :512],
// zero out[:, 512:544]).
//   grid 512 = (64 row-groups of 8) x (8 col-octs); block 512 thr = 8 waves
//   -> 2 blocks/CU, 16 waves/CU on all 256 CUs (R3 had only 4 waves/CU: the
//   60us was load-latency serialization, not bandwidth).
//   K-split INSIDE the block: wave w handles k in [64w, 64w+64); lane<->col;
//   thread = 8 rows x 1 col x 64 k = 512 FMAs (exactly the chip VALU budget
//   at 50% occupancy). x reads are wave-uniform -> scalar s_load pipe; T
//   reads coalesced 256B/wave, 8 in flight at unroll 8, each feeding 8 FMAs.
//   Wave partials reduced through LDS -> plain coalesced m stores (no
//   atomics, so no m zero-init needed). T L2 traffic: 64 row-groups x 1MB
//   = 64 MB (~1.9us at L2 BW); HBM compulsory ~2MB.
// ---------------------------------------------------------------------------
__global__ __launch_bounds__(512) void k_gemm(
    const float* __restrict__ x, const float* __restrict__ T,
    float* __restrict__ m, float* __restrict__ out) {
  const int t  = threadIdx.x;
  const int b  = blockIdx.x;
  const int rg = b >> 3;                                   // rows rg*8..+8
  const int cg = b & 7;                                    // cols cg*64..+64
  const int lane = t & 63;
  const int w    = __builtin_amdgcn_readfirstlane(t >> 6); // K-chunk 0..7
  const int col  = cg * 64 + lane;
  const int r0   = rg * 8;
  const int k0   = w * 64;

  float acc[8];
#pragma unroll
  for (int r = 0; r < 8; ++r) acc[r] = 0.f;

  const float* __restrict__ Tp = T + (size_t)k0 * NDIM + col;
  const float* __restrict__ xp = x + (size_t)r0 * FDIM + k0;  // uniform base
#pragma unroll 8
  for (int k = 0; k < 64; ++k) {
    const float tv = Tp[(size_t)k * NDIM];   // per-lane, coalesced
#pragma unroll
    for (int r = 0; r < 8; ++r)              // x: uniform addr -> s_load
      acc[r] = fmaf(xp[(size_t)r * FDIM + k], tv, acc[r]);
  }

  // combine the 8 K-chunks through LDS
  __shared__ float red[8][8][64];  // [kchunk][row][col] = 16 KB
#pragma unroll
  for (int r = 0; r < 8; ++r) red[w][r][lane] = acc[r];
  __syncthreads();
  {
    const int rr = t >> 6;  // 0..7
    float s = 0.f;
#pragma unroll
    for (int ww = 0; ww < 8; ++ww) s += red[ww][rr][lane];
    m[(size_t)(r0 + rr) * NDIM + col] = s;   // coalesced 256B/wave
  }

  // ---- output prep: g in [0, 262144) over the grid ----
  const int g = b * 512 + t;
  if (g < 65536) {  // copy x -> out[:, :512]: 512 rows x 128 float4
    const int orow = g >> 7, c4 = g & 127;
    *(float4*)(out + (size_t)orow * OUTW + c4 * 4) =
        *(const float4*)(x + (size_t)orow * FDIM + c4 * 4);
  } else if (g < 65536 + 16384) {  // zero feats cols (out poisoned pre-launch)
    const int idx = g - 65536;
    const int orow = idx >> 5, kk = idx & 31;
    out[(size_t)orow * OUTW + FDIM + kk] = 0.f;
  }
}

// ---------------------------------------------------------------------------
// Kernel 2 (unchanged from R3 — measured ~7us): feats[i,k] +=
// sum_j exp(-sum_d |m[i,k,d]-m[j,k,d]|). B-slice staged in LDS, hot loop is
// uniform LDS broadcast + VALU; 1024 blocks x 256 thr = 16 waves/CU.
// ---------------------------------------------------------------------------
__global__ __launch_bounds__(256) void k_dist(
    const float* __restrict__ m, float* __restrict__ out) {
  __shared__ float Bs[128 * DD];  // 8 KB
  __shared__ float red[256];
  const int t   = threadIdx.x;
  const int bid = blockIdx.x;
  const int ig  = bid >> 7;         // 0..7
  const int k   = (bid >> 2) & 31;  // 0..31
  const int jq  = bid & 3;          // j quarter
  const int lane = t & 63;
  const int i    = ig * 64 + lane;

  const float4* ap = (const float4*)(m + (size_t)i * NDIM + k * DD);
  const float4 A0 = ap[0], A1 = ap[1], A2 = ap[2], A3 = ap[3];

  const float* mb = m + (size_t)(jq * 128) * NDIM + k * DD;
#pragma unroll
  for (int q = 0; q < 2; ++q) {
    const int idx = q * 256 + t;        // 0..511
    const int jrow = idx >> 2, part = idx & 3;
    *(float4*)&Bs[jrow * DD + part * 4] =
        *(const float4*)(mb + (size_t)jrow * NDIM + part * 4);
  }
  __syncthreads();

  float a[DD];
  a[0]=A0.x; a[1]=A0.y; a[2]=A0.z;  a[3]=A0.w;
  a[4]=A1.x; a[5]=A1.y; a[6]=A1.z;  a[7]=A1.w;
  a[8]=A2.x; a[9]=A2.y; a[10]=A2.z; a[11]=A2.w;
  a[12]=A3.x;a[13]=A3.y;a[14]=A3.z; a[15]=A3.w;

  const int w = __builtin_amdgcn_readfirstlane(t >> 6);  // wave 0..3
  const int jbase = w * 32;
  float f = 0.f;
#pragma unroll 4
  for (int j = 0; j < 32; ++j) {
    const float4* bp = (const float4*)&Bs[(jbase + j) * DD];  // uniform
    const float4 b0 = bp[0], b1 = bp[1], b2 = bp[2], b3 = bp[3];
    float d =
        fabsf(a[0]  - b0.x) + fabsf(a[1]  - b0.y) +
        fabsf(a[2]  - b0.z) + fabsf(a[3]  - b0.w) +
        fabsf(a[4]  - b1.x) + fabsf(a[5]  - b1.y) +
        fabsf(a[6]  - b1.z) + fabsf(a[7]  - b1.w) +
        fabsf(a[8]  - b2.x) + fabsf(a[9]  - b2.y) +
        fabsf(a[10] - b2.z) + fabsf(a[11] - b2.w) +
        fabsf(a[12] - b3.x) + fabsf(a[13] - b3.y) +
        fabsf(a[14] - b3.z) + fabsf(a[15] - b3.w);
    f += __expf(-d);
  }

  red[t] = f;
  __syncthreads();
  if (t < 64) {
    const float s = red[t] + red[t + 64] + red[t + 128] + red[t + 192];
    atomicAdd(out + (size_t)(ig * 64 + t) * OUTW + FDIM + k, s);
  }
}

extern "C" void kernel_launch(void* const* d_in, const int* in_sizes, int n_in,
                              void* d_out, int out_size, void* d_ws,
                              size_t ws_size, hipStream_t stream) {
  (void)in_sizes; (void)n_in; (void)out_size; (void)ws_size;
  const float* x = (const float*)d_in[0];
  const float* T = (const float*)d_in[1];
  float* out = (float*)d_out;
  float* m   = (float*)d_ws;  // [512][512] fp32, 1 MB

  hipLaunchKernelGGL(k_gemm, dim3(512), dim3(512), 0, stream, x, T, m, out);
  hipLaunchKernelGGL(k_dist, dim3(1024), dim3(256), 0, stream, m, out);
}

// Round 5
// 72.357 us; speedup vs baseline: 1.4989x; 1.0227x over previous
//
#include <hip/hip_runtime.h>
#include <hip/hip_bf16.h>
#include <math.h>

#define BSZ 512      // batch
#define FDIM 512     // features
#define NK 32        // num_kernels
#define DD 16        // dim_per_kernel
#define NDIM (NK*DD) // 512
#define OUTW (FDIM + NK)  // 544

typedef __attribute__((ext_vector_type(8))) short short8;   // bf16x8 frag
typedef __attribute__((ext_vector_type(4))) float float4v;  // C/D frag

static __device__ __forceinline__ short f2bf(float f) {
  // RNE fp32->bf16 via HIP API (single v_cvt on gfx950)
  return (short)__builtin_bit_cast(unsigned short, __float2bfloat16(f));
}

// ---------------------------------------------------------------------------
// Kernel 1: m = x @ T via bf16 MFMA (error << 0.099 threshold: feats are
// 1 + sum exp(-d), d >~ 4). grid 1024 = 32 rg x 32 cg (16x16 output tile),
// 256 thr = 4 waves; wave w = K-chunk [128w, 128w+128) as 4 mfma 16x16x32.
// NO LDS staging: A-frag = 8 independent global dwordx4 (x k-contiguous per
// lane), B-frag = 32 independent global dword (coalesced 64B rows) -> ~40
// loads in flight per wave; latency amortized by 16 waves/CU. 4 KB LDS
// K-reduce, coalesced m store. Verified layouts: A[m=lane&15][k=8q+i],
// C/D col=lane&15 row=4q+reg (m89/m118-122).
// Also does out-prep (x -> out[:, :512], zero out[:, 512:544]).
// ---------------------------------------------------------------------------
__global__ __launch_bounds__(256) void k_gemm(
    const float* __restrict__ x, const float* __restrict__ T,
    float* __restrict__ m, float* __restrict__ out) {
  const int t  = threadIdx.x;
  const int b  = blockIdx.x;
  const int rg = b >> 5, cg = b & 31;
  const int r0 = rg * 16, c0 = cg * 16;
  const int lane = t & 63;
  const int w    = __builtin_amdgcn_readfirstlane(t >> 6);  // K-chunk 0..3
  const int mi   = lane & 15;   // A row / B col / C col
  const int q    = lane >> 4;   // quad -> k = 8q + i

  // A: x[r0+mi][128w + 8q + 32j + i]   B: T[128w + 8q + 32j + i][c0+mi]
  const float* __restrict__ xa = x + (size_t)(r0 + mi) * FDIM + 128 * w + 8 * q;
  const float* __restrict__ tb = T + (size_t)(128 * w + 8 * q) * NDIM + c0 + mi;

  float4v acc = {0.f, 0.f, 0.f, 0.f};
#pragma unroll
  for (int j = 0; j < 4; ++j) {
    const float4 a0 = *(const float4*)(xa + 32 * j);
    const float4 a1 = *(const float4*)(xa + 32 * j + 4);
    float bv[8];
#pragma unroll
    for (int i = 0; i < 8; ++i) bv[i] = tb[(size_t)(32 * j + i) * NDIM];
    short8 af, bf;
    af[0] = f2bf(a0.x); af[1] = f2bf(a0.y); af[2] = f2bf(a0.z); af[3] = f2bf(a0.w);
    af[4] = f2bf(a1.x); af[5] = f2bf(a1.y); af[6] = f2bf(a1.z); af[7] = f2bf(a1.w);
#pragma unroll
    for (int i = 0; i < 8; ++i) bf[i] = f2bf(bv[i]);
    acc = __builtin_amdgcn_mfma_f32_16x16x32_bf16(af, bf, acc, 0, 0, 0);
  }

  // K-reduce the 4 waves through LDS. C/D: col=lane&15, row=4*(lane>>4)+reg.
  __shared__ float red[4][16][16];
#pragma unroll
  for (int r = 0; r < 4; ++r) red[w][q * 4 + r][mi] = acc[r];
  __syncthreads();
  {
    const int orow = t >> 4, ocol = t & 15;
    const float s = red[0][orow][ocol] + red[1][orow][ocol] +
                    red[2][orow][ocol] + red[3][orow][ocol];
    m[(size_t)(r0 + orow) * NDIM + c0 + ocol] = s;
  }

  // ---- output prep: g in [0, 262144) over the grid ----
  const int g = b * 256 + t;
  if (g < 65536) {  // copy x -> out[:, :512]: 512 rows x 128 float4
    const int orow = g >> 7, c4 = g & 127;
    *(float4*)(out + (size_t)orow * OUTW + c4 * 4) =
        *(const float4*)(x + (size_t)orow * FDIM + c4 * 4);
  } else if (g < 65536 + 16384) {  // zero feats cols (out poisoned pre-launch)
    const int idx = g - 65536;
    const int orow = idx >> 5, kk = idx & 31;
    out[(size_t)orow * OUTW + FDIM + kk] = 0.f;
  }
}

// ---------------------------------------------------------------------------
// Kernel 2 (unchanged, ~7us measured): feats[i,k] +=
// sum_j exp(-sum_d |m[i,k,d]-m[j,k,d]|). B-slice staged in LDS, hot loop is
// uniform LDS broadcast + VALU; 1024 blocks x 256 thr = 16 waves/CU.
// ---------------------------------------------------------------------------
__global__ __launch_bounds__(256) void k_dist(
    const float* __restrict__ m, float* __restrict__ out) {
  __shared__ float Bs[128 * DD];  // 8 KB
  __shared__ float red[256];
  const int t   = threadIdx.x;
  const int bid = blockIdx.x;
  const int ig  = bid >> 7;         // 0..7
  const int k   = (bid >> 2) & 31;  // 0..31
  const int jq  = bid & 3;          // j quarter
  const int lane = t & 63;
  const int i    = ig * 64 + lane;

  const float4* ap = (const float4*)(m + (size_t)i * NDIM + k * DD);
  const float4 A0 = ap[0], A1 = ap[1], A2 = ap[2], A3 = ap[3];

  const float* mb = m + (size_t)(jq * 128) * NDIM + k * DD;
#pragma unroll
  for (int qq = 0; qq < 2; ++qq) {
    const int idx = qq * 256 + t;        // 0..511
    const int jrow = idx >> 2, part = idx & 3;
    *(float4*)&Bs[jrow * DD + part * 4] =
        *(const float4*)(mb + (size_t)jrow * NDIM + part * 4);
  }
  __syncthreads();

  float a[DD];
  a[0]=A0.x; a[1]=A0.y; a[2]=A0.z;  a[3]=A0.w;
  a[4]=A1.x; a[5]=A1.y; a[6]=A1.z;  a[7]=A1.w;
  a[8]=A2.x; a[9]=A2.y; a[10]=A2.z; a[11]=A2.w;
  a[12]=A3.x;a[13]=A3.y;a[14]=A3.z; a[15]=A3.w;

  const int w = __builtin_amdgcn_readfirstlane(t >> 6);  // wave 0..3
  const int jbase = w * 32;
  float f = 0.f;
#pragma unroll 4
  for (int j = 0; j < 32; ++j) {
    const float4* bp = (const float4*)&Bs[(jbase + j) * DD];  // uniform
    const float4 b0 = bp[0], b1 = bp[1], b2 = bp[2], b3 = bp[3];
    float d =
        fabsf(a[0]  - b0.x) + fabsf(a[1]  - b0.y) +
        fabsf(a[2]  - b0.z) + fabsf(a[3]  - b0.w) +
        fabsf(a[4]  - b1.x) + fabsf(a[5]  - b1.y) +
        fabsf(a[6]  - b1.z) + fabsf(a[7]  - b1.w) +
        fabsf(a[8]  - b2.x) + fabsf(a[9]  - b2.y) +
        fabsf(a[10] - b2.z) + fabsf(a[11] - b2.w) +
        fabsf(a[12] - b3.x) + fabsf(a[13] - b3.y) +
        fabsf(a[14] - b3.z) + fabsf(a[15] - b3.w);
    f += __expf(-d);
  }

  red[t] = f;
  __syncthreads();
  if (t < 64) {
    const float s = red[t] + red[t + 64] + red[t + 128] + red[t + 192];
    atomicAdd(out + (size_t)(ig * 64 + t) * OUTW + FDIM + k, s);
  }
}

extern "C" void kernel_launch(void* const* d_in, const int* in_sizes, int n_in,
                              void* d_out, int out_size, void* d_ws,
                              size_t ws_size, hipStream_t stream) {
  (void)in_sizes; (void)n_in; (void)out_size; (void)ws_size;
  const float* x = (const float*)d_in[0];
  const float* T = (const float*)d_in[1];
  float* out = (float*)d_out;
  float* m   = (float*)d_ws;  // [512][512] fp32, 1 MB

  hipLaunchKernelGGL(k_gemm, dim3(1024), dim3(256), 0, stream, x, T, m, out);
  hipLaunchKernelGGL(k_dist, dim3(1024), dim3(256), 0, stream, m, out);
}